// Round 9
// baseline (1017.800 us; speedup 1.0000x reference)
//
#include <hip/hip_runtime.h>
#include <stdint.h>

typedef unsigned short u16;
typedef unsigned int   u32;

#define NN 50000
#define NE 400000

typedef __bf16 bf16x8 __attribute__((ext_vector_type(8)));
typedef u16    u16x8  __attribute__((ext_vector_type(8)));
typedef u16    u16x4  __attribute__((ext_vector_type(4)));
typedef float  f32x4  __attribute__((ext_vector_type(4)));

__device__ __forceinline__ float bf2f(u16 b) {
  union { u32 u; float f; } v; v.u = ((u32)b) << 16; return v.f;
}
__device__ __forceinline__ u16 f2bf(float f) {
  union { float f; u32 u; } v; v.f = f;
  u32 r = v.u + 0x7fffu + ((v.u >> 16) & 1u);
  return (u16)(r >> 16);
}

// ---------------- setup kernels ----------------

// R5: fused zero of deg + cursor (one launch instead of two)
__global__ void zero2_kernel(int* __restrict__ a, int* __restrict__ b, int n) {
  int i = blockIdx.x * blockDim.x + threadIdx.x;
  if (i < n) { a[i] = 0; b[i] = 0; }
}

__global__ void count_deg_kernel(const int* __restrict__ dst, int* __restrict__ deg, int e) {
  int i = blockIdx.x * blockDim.x + threadIdx.x;
  if (i < e) atomicAdd(&deg[dst[i]], 1);
}

// R7: multi-block 3-launch scan (verified R8: replaced 25-40us serial scan).
// R9: dinv computation fused into part1 (it already reads deg[i]).
__global__ void scan_part1(const int* __restrict__ counts, int* __restrict__ bsum,
                           float* __restrict__ dinv, int n) {
  __shared__ int ws[4];
  int tid = threadIdx.x;
  int i = blockIdx.x * 256 + tid;
  int v = (i < n) ? counts[i] : 0;
  if (i < n) dinv[i] = rsqrtf((float)v + 1.0f);
  int s = v;
  #pragma unroll
  for (int off = 1; off < 64; off <<= 1) s += __shfl_xor(s, off, 64);
  int lane = tid & 63, wid = tid >> 6;
  if (lane == 0) ws[wid] = s;
  __syncthreads();
  if (tid == 0) bsum[blockIdx.x] = ws[0] + ws[1] + ws[2] + ws[3];
}
// part2: single block, exclusive-scan bsum in place (nb <= 256); total -> *totp
__global__ void scan_part2(int* __restrict__ bsum, int* __restrict__ totp, int nb) {
  __shared__ int ws[5];
  int tid = threadIdx.x;
  int v = (tid < nb) ? bsum[tid] : 0;
  int lane = tid & 63, wid = tid >> 6;
  int s = v;
  #pragma unroll
  for (int off = 1; off < 64; off <<= 1) {
    int t = __shfl_up(s, off, 64);
    if (lane >= off) s += t;
  }
  if (lane == 63) ws[wid] = s;
  __syncthreads();
  if (tid == 0) {
    int a = 0;
    #pragma unroll
    for (int w = 0; w < 4; ++w) { int t = ws[w]; ws[w] = a; a += t; }
    ws[4] = a;
  }
  __syncthreads();
  int ex = ws[wid] + s - v;
  if (tid < nb) bsum[tid] = ex;
  if (tid == 0) *totp = ws[4];
}
// part3: block-local exclusive scan + bsum[block] -> offsets[i]
__global__ void scan_part3(const int* __restrict__ counts, const int* __restrict__ bsum,
                           int* __restrict__ offsets, int n) {
  __shared__ int ws[5];
  int tid = threadIdx.x;
  int i = blockIdx.x * 256 + tid;
  int v = (i < n) ? counts[i] : 0;
  int lane = tid & 63, wid = tid >> 6;
  int s = v;
  #pragma unroll
  for (int off = 1; off < 64; off <<= 1) {
    int t = __shfl_up(s, off, 64);
    if (lane >= off) s += t;
  }
  if (lane == 63) ws[wid] = s;
  __syncthreads();
  if (tid == 0) {
    int a = 0;
    #pragma unroll
    for (int w = 0; w < 4; ++w) { int t = ws[w]; ws[w] = a; a += t; }
  }
  __syncthreads();
  int ex = ws[wid] + s - v;
  if (i < n) offsets[i] = bsum[blockIdx.x] + ex;
}

__global__ void csr_fill_kernel(const int* __restrict__ src, const int* __restrict__ dst,
                                const int* __restrict__ offsets, int* __restrict__ cursor,
                                const float* __restrict__ dinv,
                                int2* __restrict__ csr_pack, int e) {
  int i = blockIdx.x * blockDim.x + threadIdx.x;
  if (i < e) {
    int s = src[i], d = dst[i];
    int pos = offsets[d] + atomicAdd(&cursor[d], 1);
    float nr = dinv[s] * dinv[d];
    csr_pack[pos] = make_int2(s, __float_as_int(nr));
  }
}

// R5: vectorized f2bf (float4 in, 4x bf16 out) — G13, n must be /4
__global__ void f2bf4_kernel(const float* __restrict__ in, u16* __restrict__ out, int n4) {
  int i = blockIdx.x * blockDim.x + threadIdx.x;
  if (i < n4) {
    f32x4 v = *(const f32x4*)(in + (size_t)i * 4);
    u16x4 o;
    #pragma unroll
    for (int k = 0; k < 4; ++k) o[k] = f2bf(v[k]);
    *(u16x4*)(out + (size_t)i * 4) = o;
  }
}

// W (K x N, row-major fp32) -> Wt (N x K, row-major bf16)
__device__ __forceinline__ void wt_one(const float* W, u16* Wt, int i, int K, int N) {
  int k = i / N;
  int n2 = i - k * N;
  Wt[n2 * K + k] = f2bf(W[i]);
}

// R5: all 5 weight transposes in one launch (ranges hardcoded)
#define WT_O1 1179648   // 768*1536
#define WT_O2 2359296   // +1536*768
#define WT_O3 2654208   // +768*384
#define WT_O4 2727936   // +384*192
#define WT_O5 2728896   // +192*5
__global__ void wt_all_kernel(const float* __restrict__ W1, u16* __restrict__ W1t,
                              const float* __restrict__ W2, u16* __restrict__ W2t,
                              const float* __restrict__ W3, u16* __restrict__ W3t,
                              const float* __restrict__ W4, u16* __restrict__ W4t,
                              const float* __restrict__ W5, u16* __restrict__ W5t) {
  int i = blockIdx.x * blockDim.x + threadIdx.x;
  if (i < WT_O1)      wt_one(W1, W1t, i, 768, 1536);
  else if (i < WT_O2) wt_one(W2, W2t, i - WT_O1, 1536, 768);
  else if (i < WT_O3) wt_one(W3, W3t, i - WT_O2, 768, 384);
  else if (i < WT_O4) wt_one(W4, W4t, i - WT_O3, 384, 192);
  else if (i < WT_O5) wt_one(W5, W5t, i - WT_O4, 192, 5);
}

// ---------------- aggregation ----------------
// R8 verdict: agg16's x2 MLP was neutral -> the F=768 aggregations are
// gather-BANDWIDTH-bound (~4.2 TB/s effective L3 service on 614 MB/layer =
// ~145us floor). Do not add more in-flight loads; only byte reduction would
// move these, and fp8 would blow the absmax budget. Kernels kept as-is.

template<int G2, bool HAS_BIAS, bool RELU>
__global__ __launch_bounds__(256) void agg16_kernel(
    const u16* __restrict__ g, const int* __restrict__ rowptr,
    const int2* __restrict__ csr_pack,
    const float* __restrict__ dinv, const float* __restrict__ bias,
    u16* __restrict__ outb)
{
  constexpr int F = G2 * 16;
  int idx = blockIdx.x * blockDim.x + threadIdx.x;
  if (idx >= NN * G2) return;
  int v = idx / G2;
  int t = idx - v * G2;
  const u16* base0 = g + t * 8;
  const u16* base1 = g + (t + G2) * 8;

  float acc0[8], acc1[8];
  #pragma unroll
  for (int k = 0; k < 8; ++k) { acc0[k] = 0.f; acc1[k] = 0.f; }

  int e0 = rowptr[v], e1 = rowptr[v + 1];
  int e = e0;
  for (; e + 3 < e1; e += 4) {
    int2 p0 = csr_pack[e];
    int2 p1 = csr_pack[e + 1];
    int2 p2 = csr_pack[e + 2];
    int2 p3 = csr_pack[e + 3];
    u16x8 a0 = *(const u16x8*)(base0 + (size_t)p0.x * F);
    u16x8 b0 = *(const u16x8*)(base1 + (size_t)p0.x * F);
    u16x8 a1 = *(const u16x8*)(base0 + (size_t)p1.x * F);
    u16x8 b1 = *(const u16x8*)(base1 + (size_t)p1.x * F);
    u16x8 a2 = *(const u16x8*)(base0 + (size_t)p2.x * F);
    u16x8 b2 = *(const u16x8*)(base1 + (size_t)p2.x * F);
    u16x8 a3 = *(const u16x8*)(base0 + (size_t)p3.x * F);
    u16x8 b3 = *(const u16x8*)(base1 + (size_t)p3.x * F);
    float n0 = __int_as_float(p0.y), n1 = __int_as_float(p1.y);
    float n2 = __int_as_float(p2.y), n3 = __int_as_float(p3.y);
    #pragma unroll
    for (int k = 0; k < 8; ++k) { acc0[k] += n0 * bf2f(a0[k]); acc1[k] += n0 * bf2f(b0[k]); }
    #pragma unroll
    for (int k = 0; k < 8; ++k) { acc0[k] += n1 * bf2f(a1[k]); acc1[k] += n1 * bf2f(b1[k]); }
    #pragma unroll
    for (int k = 0; k < 8; ++k) { acc0[k] += n2 * bf2f(a2[k]); acc1[k] += n2 * bf2f(b2[k]); }
    #pragma unroll
    for (int k = 0; k < 8; ++k) { acc0[k] += n3 * bf2f(a3[k]); acc1[k] += n3 * bf2f(b3[k]); }
  }
  for (; e < e1; ++e) {
    int2 p0 = csr_pack[e];
    u16x8 a0 = *(const u16x8*)(base0 + (size_t)p0.x * F);
    u16x8 b0 = *(const u16x8*)(base1 + (size_t)p0.x * F);
    float n0 = __int_as_float(p0.y);
    #pragma unroll
    for (int k = 0; k < 8; ++k) { acc0[k] += n0 * bf2f(a0[k]); acc1[k] += n0 * bf2f(b0[k]); }
  }

  float sv = dinv[v]; sv *= sv;
  u16x8 s0 = *(const u16x8*)(base0 + (size_t)v * F);
  u16x8 s1 = *(const u16x8*)(base1 + (size_t)v * F);
  u16x8 o0, o1;
  #pragma unroll
  for (int k = 0; k < 8; ++k) {
    float v0 = acc0[k] + sv * bf2f(s0[k]);
    float v1 = acc1[k] + sv * bf2f(s1[k]);
    if (HAS_BIAS) { v0 += bias[t * 8 + k]; v1 += bias[(t + G2) * 8 + k]; }
    if (RELU) { v0 = fmaxf(v0, 0.f); v1 = fmaxf(v1, 0.f); }
    o0[k] = f2bf(v0); o1[k] = f2bf(v1);
  }
  *(u16x8*)(outb + (size_t)v * F + t * 8) = o0;
  *(u16x8*)(outb + (size_t)v * F + (t + G2) * 8) = o1;
}

// R4-verified agg8 kept for F=384/192 (halving threads/node there worsens
// wave-max-degree; R5 lesson).
template<int G, bool HAS_BIAS, bool RELU, bool OUT_BF, bool OUT_F32>
__global__ __launch_bounds__(256) void agg8_kernel(
    const u16* __restrict__ g, const int* __restrict__ rowptr,
    const int2* __restrict__ csr_pack,
    const float* __restrict__ dinv, const float* __restrict__ bias,
    u16* __restrict__ outb, float* __restrict__ outf)
{
  constexpr int F = G * 8;
  int idx = blockIdx.x * blockDim.x + threadIdx.x;
  if (idx >= NN * G) return;
  int v = idx / G;
  int g8 = idx - v * G;
  const u16* base = g + g8 * 8;

  float acc[8];
  #pragma unroll
  for (int k = 0; k < 8; ++k) acc[k] = 0.f;

  int e0 = rowptr[v], e1 = rowptr[v + 1];
  int e = e0;
  for (; e + 3 < e1; e += 4) {
    int2 p0 = csr_pack[e];
    int2 p1 = csr_pack[e + 1];
    int2 p2 = csr_pack[e + 2];
    int2 p3 = csr_pack[e + 3];
    u16x8 r0 = *(const u16x8*)(base + (size_t)p0.x * F);
    u16x8 r1 = *(const u16x8*)(base + (size_t)p1.x * F);
    u16x8 r2 = *(const u16x8*)(base + (size_t)p2.x * F);
    u16x8 r3 = *(const u16x8*)(base + (size_t)p3.x * F);
    float n0 = __int_as_float(p0.y), n1 = __int_as_float(p1.y);
    float n2 = __int_as_float(p2.y), n3 = __int_as_float(p3.y);
    #pragma unroll
    for (int k = 0; k < 8; ++k) acc[k] += n0 * bf2f(r0[k]);
    #pragma unroll
    for (int k = 0; k < 8; ++k) acc[k] += n1 * bf2f(r1[k]);
    #pragma unroll
    for (int k = 0; k < 8; ++k) acc[k] += n2 * bf2f(r2[k]);
    #pragma unroll
    for (int k = 0; k < 8; ++k) acc[k] += n3 * bf2f(r3[k]);
  }
  for (; e < e1; ++e) {
    int2 p0 = csr_pack[e];
    u16x8 r0 = *(const u16x8*)(base + (size_t)p0.x * F);
    float n0 = __int_as_float(p0.y);
    #pragma unroll
    for (int k = 0; k < 8; ++k) acc[k] += n0 * bf2f(r0[k]);
  }

  float sv = dinv[v]; sv *= sv;
  u16x8 sr = *(const u16x8*)(base + (size_t)v * F);
  float vals[8];
  #pragma unroll
  for (int k = 0; k < 8; ++k) {
    float val = acc[k] + sv * bf2f(sr[k]);
    if (HAS_BIAS) val += bias[g8 * 8 + k];
    if (RELU) val = fmaxf(val, 0.f);
    vals[k] = val;
  }
  if (OUT_BF) {
    u16x8 ob;
    #pragma unroll
    for (int k = 0; k < 8; ++k) ob[k] = f2bf(vals[k]);
    *(u16x8*)(outb + (size_t)v * F + g8 * 8) = ob;
  }
  if (OUT_F32) {
    f32x4 o0, o1;
    #pragma unroll
    for (int k = 0; k < 4; ++k) { o0[k] = vals[k]; o1[k] = vals[4 + k]; }
    float* op = outf + (size_t)v * F + g8 * 8;
    *(f32x4*)op = o0;
    *(f32x4*)(op + 4) = o1;
  }
}

// ---------------- layer 5 (N=5): skinny GEMM + aggregation ----------------
// R9: gemm_bt padded a 128-wide tile for 5 valid cols (~12us). Thread-per-row
// dot kernel instead: 24x16B row chunks, 5 dots of K=192 (W5t 1.9KB, L1-hot).
// Output rows padded to 8 u16 (16B-aligned) so the aggregation loads one u16x8
// per edge instead of 5 scalar 2B gathers.

__global__ void gemm5_kernel(const u16* __restrict__ A,      // NN x 192 bf16
                             const u16* __restrict__ W5t,    // 5 x 192 bf16
                             u16* __restrict__ Gp) {         // NN x 8 bf16 (padded)
  int row = blockIdx.x * blockDim.x + threadIdx.x;
  if (row >= NN) return;
  const u16* a = A + (size_t)row * 192;
  float acc[5] = {0.f, 0.f, 0.f, 0.f, 0.f};
  #pragma unroll
  for (int c = 0; c < 24; ++c) {
    u16x8 av = *(const u16x8*)(a + c * 8);
    float af[8];
    #pragma unroll
    for (int k = 0; k < 8; ++k) af[k] = bf2f(av[k]);
    #pragma unroll
    for (int j = 0; j < 5; ++j) {
      u16x8 wv = *(const u16x8*)(W5t + j * 192 + c * 8);
      #pragma unroll
      for (int k = 0; k < 8; ++k) acc[j] += af[k] * bf2f(wv[k]);
    }
  }
  u16x8 o;
  #pragma unroll
  for (int j = 0; j < 5; ++j) o[j] = f2bf(acc[j]);
  o[5] = 0; o[6] = 0; o[7] = 0;
  *(u16x8*)(Gp + (size_t)row * 8) = o;
}

__global__ void agg_small5_kernel(const u16* __restrict__ Gp,   // NN x 8 padded
                                  const int* __restrict__ rowptr,
                                  const int2* __restrict__ csr_pack,
                                  const float* __restrict__ dinv,
                                  const float* __restrict__ bias,
                                  float* __restrict__ out) {    // NN x 5 f32
  int v = blockIdx.x * blockDim.x + threadIdx.x;
  if (v >= NN) return;
  float acc[5] = {0.f, 0.f, 0.f, 0.f, 0.f};
  int e1 = rowptr[v + 1];
  for (int e = rowptr[v]; e < e1; ++e) {
    int2 p = csr_pack[e];
    u16x8 r = *(const u16x8*)(Gp + (size_t)p.x * 8);
    float n = __int_as_float(p.y);
    #pragma unroll
    for (int j = 0; j < 5; ++j) acc[j] += n * bf2f(r[j]);
  }
  float dv = dinv[v]; dv *= dv;
  u16x8 s = *(const u16x8*)(Gp + (size_t)v * 8);
  #pragma unroll
  for (int j = 0; j < 5; ++j)
    out[(size_t)v * 5 + j] = acc[j] + dv * bf2f(s[j]) + bias[j];
}

// ---------------- GEMM (A: MxK bf16 row-major, Bt: NxK bf16 row-major) ----------------
// R5 DECISION: 128x128 m97-structure for ALL big layers (measured 199.5us/25.4%/
// 41%occ; the 256x256 deep-pipeline arc R1/R3/R4 never beat it — do not revisit
// without new counter evidence). XCD supertile + quad swizzle (conflicts 0) +
// dbuf K-loop + __launch_bounds__(256,4).

#define BM 128
#define BN 128
#define BK 32

// gfx9 s_waitcnt simm16: vmcnt[3:0]|expcnt[6:4]|lgkmcnt[11:8]|vmcnt_hi[15:14]
#define WAIT_VMCNT4 0x0F74   // vmcnt(4), lgkm/exp = no-wait
#define WAIT_VMCNT0 0x0F70   // vmcnt(0), lgkm/exp = no-wait

__device__ __forceinline__ void gl_lds16(const void* g, void* l) {
  __builtin_amdgcn_global_load_lds((const __attribute__((address_space(1))) void*)g,
                                   (__attribute__((address_space(3))) void*)l, 16, 0, 0);
}

template<bool BIAS_RELU>
__global__ __launch_bounds__(256, 4) void gemm_bt_kernel(
    const u16* __restrict__ A, const u16* __restrict__ Bt,
    u16* __restrict__ C, const float* __restrict__ bias,
    int M, int N, int K)
{
  __shared__ __align__(16) u16 As[2][BM * BK];
  __shared__ __align__(16) u16 Bs[2][BN * BK];
  int gm = (M + BM - 1) / BM;
  int gn = (N + BN - 1) / BN;
  int bid = blockIdx.x;
  int xcd = bid & 7;
  int t = bid >> 3;
  int trow = t / gn;
  int bn_i = t - trow * gn;
  int row = trow * 8 + xcd;
  if (row >= gm) return;
  int bm = row * BM, bn = bn_i * BN;

  int tid = threadIdx.x;
  int wave = tid >> 6, lane = tid & 63;
  int wm = wave & 1, wn = wave >> 1;

  // staging: 4 lanes per 32-elem row; logical quad permuted -> swizzled LDS layout
  int srow = tid >> 2;                                // 0..63
  int sq_log = ((tid & 3) - ((tid >> 3) & 3)) & 3;    // logical quad this lane stages
  int ar0 = min(bm + srow, M - 1);
  int ar1 = min(bm + 64 + srow, M - 1);
  int br0 = min(bn + srow, N - 1);
  int br1 = min(bn + 64 + srow, N - 1);
  const u16* ag0 = A + (size_t)ar0 * K + sq_log * 8;
  const u16* ag1 = A + (size_t)ar1 * K + sq_log * 8;
  const u16* bg0 = Bt + (size_t)br0 * K + sq_log * 8;
  const u16* bg1 = Bt + (size_t)br1 * K + sq_log * 8;
  int la0 = (wave * 16) * BK;
  int la1 = (64 + wave * 16) * BK;

  f32x4 acc[4][4];
  #pragma unroll
  for (int i = 0; i < 4; ++i)
    #pragma unroll
    for (int j = 0; j < 4; ++j)
      acc[i][j] = (f32x4){0.f, 0.f, 0.f, 0.f};

  int row16 = lane & 15, q = lane >> 4;
  int perm = (q + (row16 >> 1)) & 3;                  // physical quad for logical quad q
  int ard = (wm * 64 + row16) * BK + perm * 8;
  int brd = (wn * 64 + row16) * BK + perm * 8;

  const int iters = K / BK;

  // prologue: stage tile 0 into buffer 0
  gl_lds16(ag0, &As[0][la0]);
  gl_lds16(ag1, &As[0][la1]);
  gl_lds16(bg0, &Bs[0][la0]);
  gl_lds16(bg1, &Bs[0][la1]);

  int buf = 0;
  for (int it = 0; it < iters; ++it) {
    __builtin_amdgcn_s_barrier();
    if (it + 1 < iters) {
      int kn = (it + 1) * BK;
      gl_lds16(ag0 + kn, &As[buf ^ 1][la0]);
      gl_lds16(ag1 + kn, &As[buf ^ 1][la1]);
      gl_lds16(bg0 + kn, &Bs[buf ^ 1][la0]);
      gl_lds16(bg1 + kn, &Bs[buf ^ 1][la1]);
      __builtin_amdgcn_s_waitcnt(WAIT_VMCNT4);  // wait only current buf's 4 loads
    } else {
      __builtin_amdgcn_s_waitcnt(WAIT_VMCNT0);
    }
    __builtin_amdgcn_s_barrier();

    bf16x8 af[4], bfr[4];
    #pragma unroll
    for (int i = 0; i < 4; ++i) af[i] = *(const bf16x8*)(&As[buf][ard + i * 16 * BK]);
    #pragma unroll
    for (int j = 0; j < 4; ++j) bfr[j] = *(const bf16x8*)(&Bs[buf][brd + j * 16 * BK]);
    #pragma unroll
    for (int i = 0; i < 4; ++i)
      #pragma unroll
      for (int j = 0; j < 4; ++j)
        acc[i][j] = __builtin_amdgcn_mfma_f32_16x16x32_bf16(af[i], bfr[j], acc[i][j], 0, 0, 0);
    buf ^= 1;
  }

  // epilogue: C/D layout col=lane&15, row=(lane>>4)*4+reg  [verified m89/m91]
  #pragma unroll
  for (int i = 0; i < 4; ++i) {
    int rbase = bm + wm * 64 + i * 16 + q * 4;
    #pragma unroll
    for (int j = 0; j < 4; ++j) {
      int col = bn + wn * 64 + j * 16 + row16;
      if (col < N) {
        float bv = BIAS_RELU ? bias[col] : 0.f;
        #pragma unroll
        for (int r = 0; r < 4; ++r) {
          int gr = rbase + r;
          if (gr < M) {
            float val = acc[i][j][r];
            if (BIAS_RELU) { val += bv; val = fmaxf(val, 0.f); }
            C[(size_t)gr * N + col] = f2bf(val);
          }
        }
      }
    }
  }
}

static inline int gemm_grid(int M, int N) {
  int gm = (M + BM - 1) / BM;
  int gn = (N + BN - 1) / BN;
  int rows_per_xcd = (gm + 7) / 8;
  return rows_per_xcd * gn * 8;
}

// ---------------- launch ----------------

extern "C" void kernel_launch(void* const* d_in, const int* in_sizes, int n_in,
                              void* d_out, int out_size, void* d_ws, size_t ws_size,
                              hipStream_t stream) {
  const float* x   = (const float*)d_in[0];
  const int* ei    = (const int*)d_in[1];
  const int* src   = ei;
  const int* dst   = ei + NE;
  const float* W1  = (const float*)d_in[2];
  const float* b1  = (const float*)d_in[3];
  const float* W2  = (const float*)d_in[4];
  const float* b2  = (const float*)d_in[5];
  const float* W3  = (const float*)d_in[6];
  const float* b3  = (const float*)d_in[7];
  const float* W4  = (const float*)d_in[8];
  const float* b4  = (const float*)d_in[9];
  const float* W5  = (const float*)d_in[10];
  const float* b5  = (const float*)d_in[11];
  float* out_h = (float*)d_out;                       // 50000 x 192
  float* out_o = (float*)d_out + (size_t)NN * 192;    // 50000 x 5

  char* p = (char*)d_ws;
  auto alloc = [&](size_t bytes) { char* r = p; p += (bytes + 255) & ~(size_t)255; return r; };
  int*   deg      = (int*)alloc((size_t)NN * 4);
  int*   cursor   = (int*)alloc((size_t)NN * 4);
  float* dinv     = (float*)alloc((size_t)NN * 4);
  int*   offs     = (int*)alloc((size_t)(NN + 1) * 4);
  int*   bsum     = (int*)alloc((size_t)256 * 4);
  int2*  csr_pack = (int2*)alloc((size_t)NE * 8);
  u16* W1t = (u16*)alloc((size_t)768 * 1536 * 2);
  u16* W2t = (u16*)alloc((size_t)1536 * 768 * 2);
  u16* W3t = (u16*)alloc((size_t)768 * 384 * 2);
  u16* W4t = (u16*)alloc((size_t)384 * 192 * 2);
  u16* W5t = (u16*)alloc((size_t)192 * 5 * 2);
  u16* B0 = (u16*)alloc((size_t)NN * 768 * 2);
  u16* B1 = (u16*)alloc((size_t)NN * 768 * 2);
  u16* B2 = (u16*)alloc((size_t)NN * 1536 * 2);

  u16* xb  = B0;
  u16* a0  = B1;
  u16* h1  = B2;
  u16* g2  = B0;
  u16* h2  = B1;
  u16* g3  = B0;
  u16* h3  = B2;
  u16* g4  = B0;
  u16* h4b = B1;
  u16* g5p = B0;   // padded NN x 8

  const int M = NN;
  const int NBLK = (NN + 255) / 256;   // 196 blocks

  // degree / CSR build (R9: dinv fused into scan_part1)
  zero2_kernel<<<NBLK, 256, 0, stream>>>(deg, cursor, NN);
  count_deg_kernel<<<(NE + 255) / 256, 256, 0, stream>>>(dst, deg, NE);
  scan_part1<<<NBLK, 256, 0, stream>>>(deg, bsum, dinv, NN);
  scan_part2<<<1, 256, 0, stream>>>(bsum, offs + NN, NBLK);
  scan_part3<<<NBLK, 256, 0, stream>>>(deg, bsum, offs, NN);
  csr_fill_kernel<<<(NE + 255) / 256, 256, 0, stream>>>(src, dst, offs, cursor, dinv,
                                                        csr_pack, NE);
  // dtype conversions (R5: vectorized f2bf; all weight transposes in one launch)
  f2bf4_kernel<<<((NN * 768 / 4) + 255) / 256, 256, 0, stream>>>(x, xb, NN * 768 / 4);
  wt_all_kernel<<<(WT_O5 + 255) / 256, 256, 0, stream>>>(W1, W1t, W2, W2t, W3, W3t,
                                                         W4, W4t, W5, W5t);

  dim3 blk(256);

  // layer 1: aggregate-first  (Ahat x) W1 + b1, relu
  agg16_kernel<48, false, false><<<(NN * 48 + 255) / 256, blk, 0, stream>>>(
      xb, offs, csr_pack, dinv, nullptr, a0);
  gemm_bt_kernel<true><<<gemm_grid(M, 1536), blk, 0, stream>>>(
      a0, W1t, h1, b1, M, 1536, 768);

  // layer 2
  gemm_bt_kernel<false><<<gemm_grid(M, 768), blk, 0, stream>>>(
      h1, W2t, g2, nullptr, M, 768, 1536);
  agg16_kernel<48, true, true><<<(NN * 48 + 255) / 256, blk, 0, stream>>>(
      g2, offs, csr_pack, dinv, b2, h2);

  // layer 3
  gemm_bt_kernel<false><<<gemm_grid(M, 384), blk, 0, stream>>>(
      h2, W3t, g3, nullptr, M, 384, 768);
  agg8_kernel<48, true, true, true, false><<<(NN * 48 + 255) / 256, blk, 0, stream>>>(
      g3, offs, csr_pack, dinv, b3, h3, nullptr);

  // layer 4 (output 0: fp32 h to d_out, bf16 copy for layer 5)
  gemm_bt_kernel<false><<<gemm_grid(M, 192), blk, 0, stream>>>(
      h3, W4t, g4, nullptr, M, 192, 384);
  agg8_kernel<24, true, true, true, true><<<(NN * 24 + 255) / 256, blk, 0, stream>>>(
      g4, offs, csr_pack, dinv, b4, h4b, out_h);

  // layer 5 (output 1): skinny row-dot GEMM (padded rows) + u16x8 aggregation
  gemm5_kernel<<<NBLK, 256, 0, stream>>>(h4b, W5t, g5p);
  agg_small5_kernel<<<NBLK, 256, 0, stream>>>(g5p, offs, csr_pack, dinv, b5, out_o);
}

// Round 10
// 1017.152 us; speedup vs baseline: 1.0006x; 1.0006x over previous
//
#include <hip/hip_runtime.h>
#include <stdint.h>

typedef unsigned short u16;
typedef unsigned int   u32;

#define NN 50000
#define NE 400000

typedef __bf16 bf16x8 __attribute__((ext_vector_type(8)));
typedef u16    u16x8  __attribute__((ext_vector_type(8)));
typedef u16    u16x4  __attribute__((ext_vector_type(4)));
typedef float  f32x4  __attribute__((ext_vector_type(4)));

__device__ __forceinline__ float bf2f(u16 b) {
  union { u32 u; float f; } v; v.u = ((u32)b) << 16; return v.f;
}
__device__ __forceinline__ u16 f2bf(float f) {
  union { float f; u32 u; } v; v.f = f;
  u32 r = v.u + 0x7fffu + ((v.u >> 16) & 1u);
  return (u16)(r >> 16);
}

// ---------------- setup kernels ----------------

// R5: fused zero of deg + cursor (one launch instead of two)
__global__ void zero2_kernel(int* __restrict__ a, int* __restrict__ b, int n) {
  int i = blockIdx.x * blockDim.x + threadIdx.x;
  if (i < n) { a[i] = 0; b[i] = 0; }
}

__global__ void count_deg_kernel(const int* __restrict__ dst, int* __restrict__ deg, int e) {
  int i = blockIdx.x * blockDim.x + threadIdx.x;
  if (i < e) atomicAdd(&deg[dst[i]], 1);
}

// R7: multi-block 3-launch scan (verified R8: replaced 25-40us serial scan).
// R9: dinv computation fused into part1 (it already reads deg[i]).
__global__ void scan_part1(const int* __restrict__ counts, int* __restrict__ bsum,
                           float* __restrict__ dinv, int n) {
  __shared__ int ws[4];
  int tid = threadIdx.x;
  int i = blockIdx.x * 256 + tid;
  int v = (i < n) ? counts[i] : 0;
  if (i < n) dinv[i] = rsqrtf((float)v + 1.0f);
  int s = v;
  #pragma unroll
  for (int off = 1; off < 64; off <<= 1) s += __shfl_xor(s, off, 64);
  int lane = tid & 63, wid = tid >> 6;
  if (lane == 0) ws[wid] = s;
  __syncthreads();
  if (tid == 0) bsum[blockIdx.x] = ws[0] + ws[1] + ws[2] + ws[3];
}
// part2: single block, exclusive-scan bsum in place (nb <= 256); total -> *totp
__global__ void scan_part2(int* __restrict__ bsum, int* __restrict__ totp, int nb) {
  __shared__ int ws[5];
  int tid = threadIdx.x;
  int v = (tid < nb) ? bsum[tid] : 0;
  int lane = tid & 63, wid = tid >> 6;
  int s = v;
  #pragma unroll
  for (int off = 1; off < 64; off <<= 1) {
    int t = __shfl_up(s, off, 64);
    if (lane >= off) s += t;
  }
  if (lane == 63) ws[wid] = s;
  __syncthreads();
  if (tid == 0) {
    int a = 0;
    #pragma unroll
    for (int w = 0; w < 4; ++w) { int t = ws[w]; ws[w] = a; a += t; }
    ws[4] = a;
  }
  __syncthreads();
  int ex = ws[wid] + s - v;
  if (tid < nb) bsum[tid] = ex;
  if (tid == 0) *totp = ws[4];
}
// part3: block-local exclusive scan + bsum[block] -> offsets[i]
__global__ void scan_part3(const int* __restrict__ counts, const int* __restrict__ bsum,
                           int* __restrict__ offsets, int n) {
  __shared__ int ws[5];
  int tid = threadIdx.x;
  int i = blockIdx.x * 256 + tid;
  int v = (i < n) ? counts[i] : 0;
  int lane = tid & 63, wid = tid >> 6;
  int s = v;
  #pragma unroll
  for (int off = 1; off < 64; off <<= 1) {
    int t = __shfl_up(s, off, 64);
    if (lane >= off) s += t;
  }
  if (lane == 63) ws[wid] = s;
  __syncthreads();
  if (tid == 0) {
    int a = 0;
    #pragma unroll
    for (int w = 0; w < 4; ++w) { int t = ws[w]; ws[w] = a; a += t; }
  }
  __syncthreads();
  int ex = ws[wid] + s - v;
  if (i < n) offsets[i] = bsum[blockIdx.x] + ex;
}

__global__ void csr_fill_kernel(const int* __restrict__ src, const int* __restrict__ dst,
                                const int* __restrict__ offsets, int* __restrict__ cursor,
                                const float* __restrict__ dinv,
                                int2* __restrict__ csr_pack, int e) {
  int i = blockIdx.x * blockDim.x + threadIdx.x;
  if (i < e) {
    int s = src[i], d = dst[i];
    int pos = offsets[d] + atomicAdd(&cursor[d], 1);
    float nr = dinv[s] * dinv[d];
    csr_pack[pos] = make_int2(s, __float_as_int(nr));
  }
}

// R5: vectorized f2bf (float4 in, 4x bf16 out) — G13, n must be /4
__global__ void f2bf4_kernel(const float* __restrict__ in, u16* __restrict__ out, int n4) {
  int i = blockIdx.x * blockDim.x + threadIdx.x;
  if (i < n4) {
    f32x4 v = *(const f32x4*)(in + (size_t)i * 4);
    u16x4 o;
    #pragma unroll
    for (int k = 0; k < 4; ++k) o[k] = f2bf(v[k]);
    *(u16x4*)(out + (size_t)i * 4) = o;
  }
}

// W (K x N, row-major fp32) -> Wt (N x K, row-major bf16)
__device__ __forceinline__ void wt_one(const float* W, u16* Wt, int i, int K, int N) {
  int k = i / N;
  int n2 = i - k * N;
  Wt[n2 * K + k] = f2bf(W[i]);
}

// R5: all 5 weight transposes in one launch (ranges hardcoded)
#define WT_O1 1179648   // 768*1536
#define WT_O2 2359296   // +1536*768
#define WT_O3 2654208   // +768*384
#define WT_O4 2727936   // +384*192
#define WT_O5 2728896   // +192*5
__global__ void wt_all_kernel(const float* __restrict__ W1, u16* __restrict__ W1t,
                              const float* __restrict__ W2, u16* __restrict__ W2t,
                              const float* __restrict__ W3, u16* __restrict__ W3t,
                              const float* __restrict__ W4, u16* __restrict__ W4t,
                              const float* __restrict__ W5, u16* __restrict__ W5t) {
  int i = blockIdx.x * blockDim.x + threadIdx.x;
  if (i < WT_O1)      wt_one(W1, W1t, i, 768, 1536);
  else if (i < WT_O2) wt_one(W2, W2t, i - WT_O1, 1536, 768);
  else if (i < WT_O3) wt_one(W3, W3t, i - WT_O2, 768, 384);
  else if (i < WT_O4) wt_one(W4, W4t, i - WT_O3, 384, 192);
  else if (i < WT_O5) wt_one(W5, W5t, i - WT_O4, 192, 5);
}

// ---------------- aggregation ----------------
// R8 verdict: agg16's x2 MLP was neutral -> the F=768 aggregations are
// gather-BANDWIDTH-bound (~4.2 TB/s effective on 614 MB/layer = ~145us floor).
// Byte reduction (fp8) would blow the absmax budget. Kernels kept as-is.

template<int G2, bool HAS_BIAS, bool RELU>
__global__ __launch_bounds__(256) void agg16_kernel(
    const u16* __restrict__ g, const int* __restrict__ rowptr,
    const int2* __restrict__ csr_pack,
    const float* __restrict__ dinv, const float* __restrict__ bias,
    u16* __restrict__ outb)
{
  constexpr int F = G2 * 16;
  int idx = blockIdx.x * blockDim.x + threadIdx.x;
  if (idx >= NN * G2) return;
  int v = idx / G2;
  int t = idx - v * G2;
  const u16* base0 = g + t * 8;
  const u16* base1 = g + (t + G2) * 8;

  float acc0[8], acc1[8];
  #pragma unroll
  for (int k = 0; k < 8; ++k) { acc0[k] = 0.f; acc1[k] = 0.f; }

  int e0 = rowptr[v], e1 = rowptr[v + 1];
  int e = e0;
  for (; e + 3 < e1; e += 4) {
    int2 p0 = csr_pack[e];
    int2 p1 = csr_pack[e + 1];
    int2 p2 = csr_pack[e + 2];
    int2 p3 = csr_pack[e + 3];
    u16x8 a0 = *(const u16x8*)(base0 + (size_t)p0.x * F);
    u16x8 b0 = *(const u16x8*)(base1 + (size_t)p0.x * F);
    u16x8 a1 = *(const u16x8*)(base0 + (size_t)p1.x * F);
    u16x8 b1 = *(const u16x8*)(base1 + (size_t)p1.x * F);
    u16x8 a2 = *(const u16x8*)(base0 + (size_t)p2.x * F);
    u16x8 b2 = *(const u16x8*)(base1 + (size_t)p2.x * F);
    u16x8 a3 = *(const u16x8*)(base0 + (size_t)p3.x * F);
    u16x8 b3 = *(const u16x8*)(base1 + (size_t)p3.x * F);
    float n0 = __int_as_float(p0.y), n1 = __int_as_float(p1.y);
    float n2 = __int_as_float(p2.y), n3 = __int_as_float(p3.y);
    #pragma unroll
    for (int k = 0; k < 8; ++k) { acc0[k] += n0 * bf2f(a0[k]); acc1[k] += n0 * bf2f(b0[k]); }
    #pragma unroll
    for (int k = 0; k < 8; ++k) { acc0[k] += n1 * bf2f(a1[k]); acc1[k] += n1 * bf2f(b1[k]); }
    #pragma unroll
    for (int k = 0; k < 8; ++k) { acc0[k] += n2 * bf2f(a2[k]); acc1[k] += n2 * bf2f(b2[k]); }
    #pragma unroll
    for (int k = 0; k < 8; ++k) { acc0[k] += n3 * bf2f(a3[k]); acc1[k] += n3 * bf2f(b3[k]); }
  }
  for (; e < e1; ++e) {
    int2 p0 = csr_pack[e];
    u16x8 a0 = *(const u16x8*)(base0 + (size_t)p0.x * F);
    u16x8 b0 = *(const u16x8*)(base1 + (size_t)p0.x * F);
    float n0 = __int_as_float(p0.y);
    #pragma unroll
    for (int k = 0; k < 8; ++k) { acc0[k] += n0 * bf2f(a0[k]); acc1[k] += n0 * bf2f(b0[k]); }
  }

  float sv = dinv[v]; sv *= sv;
  u16x8 s0 = *(const u16x8*)(base0 + (size_t)v * F);
  u16x8 s1 = *(const u16x8*)(base1 + (size_t)v * F);
  u16x8 o0, o1;
  #pragma unroll
  for (int k = 0; k < 8; ++k) {
    float v0 = acc0[k] + sv * bf2f(s0[k]);
    float v1 = acc1[k] + sv * bf2f(s1[k]);
    if (HAS_BIAS) { v0 += bias[t * 8 + k]; v1 += bias[(t + G2) * 8 + k]; }
    if (RELU) { v0 = fmaxf(v0, 0.f); v1 = fmaxf(v1, 0.f); }
    o0[k] = f2bf(v0); o1[k] = f2bf(v1);
  }
  *(u16x8*)(outb + (size_t)v * F + t * 8) = o0;
  *(u16x8*)(outb + (size_t)v * F + (t + G2) * 8) = o1;
}

// R4-verified agg8 kept for F=384/192 (halving threads/node there worsens
// wave-max-degree; R5 lesson).
template<int G, bool HAS_BIAS, bool RELU, bool OUT_BF, bool OUT_F32>
__global__ __launch_bounds__(256) void agg8_kernel(
    const u16* __restrict__ g, const int* __restrict__ rowptr,
    const int2* __restrict__ csr_pack,
    const float* __restrict__ dinv, const float* __restrict__ bias,
    u16* __restrict__ outb, float* __restrict__ outf)
{
  constexpr int F = G * 8;
  int idx = blockIdx.x * blockDim.x + threadIdx.x;
  if (idx >= NN * G) return;
  int v = idx / G;
  int g8 = idx - v * G;
  const u16* base = g + g8 * 8;

  float acc[8];
  #pragma unroll
  for (int k = 0; k < 8; ++k) acc[k] = 0.f;

  int e0 = rowptr[v], e1 = rowptr[v + 1];
  int e = e0;
  for (; e + 3 < e1; e += 4) {
    int2 p0 = csr_pack[e];
    int2 p1 = csr_pack[e + 1];
    int2 p2 = csr_pack[e + 2];
    int2 p3 = csr_pack[e + 3];
    u16x8 r0 = *(const u16x8*)(base + (size_t)p0.x * F);
    u16x8 r1 = *(const u16x8*)(base + (size_t)p1.x * F);
    u16x8 r2 = *(const u16x8*)(base + (size_t)p2.x * F);
    u16x8 r3 = *(const u16x8*)(base + (size_t)p3.x * F);
    float n0 = __int_as_float(p0.y), n1 = __int_as_float(p1.y);
    float n2 = __int_as_float(p2.y), n3 = __int_as_float(p3.y);
    #pragma unroll
    for (int k = 0; k < 8; ++k) acc[k] += n0 * bf2f(r0[k]);
    #pragma unroll
    for (int k = 0; k < 8; ++k) acc[k] += n1 * bf2f(r1[k]);
    #pragma unroll
    for (int k = 0; k < 8; ++k) acc[k] += n2 * bf2f(r2[k]);
    #pragma unroll
    for (int k = 0; k < 8; ++k) acc[k] += n3 * bf2f(r3[k]);
  }
  for (; e < e1; ++e) {
    int2 p0 = csr_pack[e];
    u16x8 r0 = *(const u16x8*)(base + (size_t)p0.x * F);
    float n0 = __int_as_float(p0.y);
    #pragma unroll
    for (int k = 0; k < 8; ++k) acc[k] += n0 * bf2f(r0[k]);
  }

  float sv = dinv[v]; sv *= sv;
  u16x8 sr = *(const u16x8*)(base + (size_t)v * F);
  float vals[8];
  #pragma unroll
  for (int k = 0; k < 8; ++k) {
    float val = acc[k] + sv * bf2f(sr[k]);
    if (HAS_BIAS) val += bias[g8 * 8 + k];
    if (RELU) val = fmaxf(val, 0.f);
    vals[k] = val;
  }
  if (OUT_BF) {
    u16x8 ob;
    #pragma unroll
    for (int k = 0; k < 8; ++k) ob[k] = f2bf(vals[k]);
    *(u16x8*)(outb + (size_t)v * F + g8 * 8) = ob;
  }
  if (OUT_F32) {
    f32x4 o0, o1;
    #pragma unroll
    for (int k = 0; k < 4; ++k) { o0[k] = vals[k]; o1[k] = vals[4 + k]; }
    float* op = outf + (size_t)v * F + g8 * 8;
    *(f32x4*)op = o0;
    *(f32x4*)(op + 4) = o1;
  }
}

// ---------------- layer 5 (N=5): skinny GEMM + aggregation (R9) ----------------

__global__ void gemm5_kernel(const u16* __restrict__ A,      // NN x 192 bf16
                             const u16* __restrict__ W5t,    // 5 x 192 bf16
                             u16* __restrict__ Gp) {         // NN x 8 bf16 (padded)
  int row = blockIdx.x * blockDim.x + threadIdx.x;
  if (row >= NN) return;
  const u16* a = A + (size_t)row * 192;
  float acc[5] = {0.f, 0.f, 0.f, 0.f, 0.f};
  #pragma unroll
  for (int c = 0; c < 24; ++c) {
    u16x8 av = *(const u16x8*)(a + c * 8);
    float af[8];
    #pragma unroll
    for (int k = 0; k < 8; ++k) af[k] = bf2f(av[k]);
    #pragma unroll
    for (int j = 0; j < 5; ++j) {
      u16x8 wv = *(const u16x8*)(W5t + j * 192 + c * 8);
      #pragma unroll
      for (int k = 0; k < 8; ++k) acc[j] += af[k] * bf2f(wv[k]);
    }
  }
  u16x8 o;
  #pragma unroll
  for (int j = 0; j < 5; ++j) o[j] = f2bf(acc[j]);
  o[5] = 0; o[6] = 0; o[7] = 0;
  *(u16x8*)(Gp + (size_t)row * 8) = o;
}

__global__ void agg_small5_kernel(const u16* __restrict__ Gp,   // NN x 8 padded
                                  const int* __restrict__ rowptr,
                                  const int2* __restrict__ csr_pack,
                                  const float* __restrict__ dinv,
                                  const float* __restrict__ bias,
                                  float* __restrict__ out) {    // NN x 5 f32
  int v = blockIdx.x * blockDim.x + threadIdx.x;
  if (v >= NN) return;
  float acc[5] = {0.f, 0.f, 0.f, 0.f, 0.f};
  int e1 = rowptr[v + 1];
  for (int e = rowptr[v]; e < e1; ++e) {
    int2 p = csr_pack[e];
    u16x8 r = *(const u16x8*)(Gp + (size_t)p.x * 8);
    float n = __int_as_float(p.y);
    #pragma unroll
    for (int j = 0; j < 5; ++j) acc[j] += n * bf2f(r[j]);
  }
  float dv = dinv[v]; dv *= dv;
  u16x8 s = *(const u16x8*)(Gp + (size_t)v * 8);
  #pragma unroll
  for (int j = 0; j < 5; ++j)
    out[(size_t)v * 5 + j] = acc[j] + dv * bf2f(s[j]) + bias[j];
}

// ---------------- GEMM (A: MxK bf16 row-major, Bt: NxK bf16 row-major) ----------------
// R5 DECISION: 128x128 m97-structure for ALL big layers (measured 199.5us/25.4%/
// 41%occ; the 256x256 deep-pipeline arc R1/R3/R4 never beat it). XCD supertile +
// quad swizzle (conflicts 0) + dbuf K-loop + __launch_bounds__(256,4).
// R10: SWAPPED-OPERAND MFMA epilogue. mfma(bfr[j], af[i], acc) computes the
// transposed tile, so the verified D-mapping (col=lane&15, row=(lane>>4)*4+reg,
// m89/m91) now lands reg r on 4 CONSECUTIVE C columns at one row:
//   C-row = bm + wm*64 + i*16 + (lane&15)
//   C-col = bn + wn*64 + j*16 + (lane>>4)*4 + r
// -> 16 aligned 8B u16x4 stores/thread instead of 64 scalar 2B stores (write
// amplification was WRITE_SIZE 178MB vs 154MB ideal). A/B fragments have
// identical per-lane layouts for 16x16x32 so the swap is exact. K-loop,
// staging, swizzle unchanged.

#define BM 128
#define BN 128
#define BK 32

// gfx9 s_waitcnt simm16: vmcnt[3:0]|expcnt[6:4]|lgkmcnt[11:8]|vmcnt_hi[15:14]
#define WAIT_VMCNT4 0x0F74   // vmcnt(4), lgkm/exp = no-wait
#define WAIT_VMCNT0 0x0F70   // vmcnt(0), lgkm/exp = no-wait

__device__ __forceinline__ void gl_lds16(const void* g, void* l) {
  __builtin_amdgcn_global_load_lds((const __attribute__((address_space(1))) void*)g,
                                   (__attribute__((address_space(3))) void*)l, 16, 0, 0);
}

template<bool BIAS_RELU>
__global__ __launch_bounds__(256, 4) void gemm_bt_kernel(
    const u16* __restrict__ A, const u16* __restrict__ Bt,
    u16* __restrict__ C, const float* __restrict__ bias,
    int M, int N, int K)
{
  __shared__ __align__(16) u16 As[2][BM * BK];
  __shared__ __align__(16) u16 Bs[2][BN * BK];
  int gm = (M + BM - 1) / BM;
  int gn = (N + BN - 1) / BN;
  int bid = blockIdx.x;
  int xcd = bid & 7;
  int t = bid >> 3;
  int trow = t / gn;
  int bn_i = t - trow * gn;
  int row = trow * 8 + xcd;
  if (row >= gm) return;
  int bm = row * BM, bn = bn_i * BN;

  int tid = threadIdx.x;
  int wave = tid >> 6, lane = tid & 63;
  int wm = wave & 1, wn = wave >> 1;

  // staging: 4 lanes per 32-elem row; logical quad permuted -> swizzled LDS layout
  int srow = tid >> 2;                                // 0..63
  int sq_log = ((tid & 3) - ((tid >> 3) & 3)) & 3;    // logical quad this lane stages
  int ar0 = min(bm + srow, M - 1);
  int ar1 = min(bm + 64 + srow, M - 1);
  int br0 = min(bn + srow, N - 1);
  int br1 = min(bn + 64 + srow, N - 1);
  const u16* ag0 = A + (size_t)ar0 * K + sq_log * 8;
  const u16* ag1 = A + (size_t)ar1 * K + sq_log * 8;
  const u16* bg0 = Bt + (size_t)br0 * K + sq_log * 8;
  const u16* bg1 = Bt + (size_t)br1 * K + sq_log * 8;
  int la0 = (wave * 16) * BK;
  int la1 = (64 + wave * 16) * BK;

  f32x4 acc[4][4];
  #pragma unroll
  for (int i = 0; i < 4; ++i)
    #pragma unroll
    for (int j = 0; j < 4; ++j)
      acc[i][j] = (f32x4){0.f, 0.f, 0.f, 0.f};

  int row16 = lane & 15, q = lane >> 4;
  int perm = (q + (row16 >> 1)) & 3;                  // physical quad for logical quad q
  int ard = (wm * 64 + row16) * BK + perm * 8;
  int brd = (wn * 64 + row16) * BK + perm * 8;

  const int iters = K / BK;

  // prologue: stage tile 0 into buffer 0
  gl_lds16(ag0, &As[0][la0]);
  gl_lds16(ag1, &As[0][la1]);
  gl_lds16(bg0, &Bs[0][la0]);
  gl_lds16(bg1, &Bs[0][la1]);

  int buf = 0;
  for (int it = 0; it < iters; ++it) {
    __builtin_amdgcn_s_barrier();
    if (it + 1 < iters) {
      int kn = (it + 1) * BK;
      gl_lds16(ag0 + kn, &As[buf ^ 1][la0]);
      gl_lds16(ag1 + kn, &As[buf ^ 1][la1]);
      gl_lds16(bg0 + kn, &Bs[buf ^ 1][la0]);
      gl_lds16(bg1 + kn, &Bs[buf ^ 1][la1]);
      __builtin_amdgcn_s_waitcnt(WAIT_VMCNT4);  // wait only current buf's 4 loads
    } else {
      __builtin_amdgcn_s_waitcnt(WAIT_VMCNT0);
    }
    __builtin_amdgcn_s_barrier();

    bf16x8 af[4], bfr[4];
    #pragma unroll
    for (int i = 0; i < 4; ++i) af[i] = *(const bf16x8*)(&As[buf][ard + i * 16 * BK]);
    #pragma unroll
    for (int j = 0; j < 4; ++j) bfr[j] = *(const bf16x8*)(&Bs[buf][brd + j * 16 * BK]);
    // R10: operands swapped -> acc[i][j] holds the transposed sub-tile
    #pragma unroll
    for (int i = 0; i < 4; ++i)
      #pragma unroll
      for (int j = 0; j < 4; ++j)
        acc[i][j] = __builtin_amdgcn_mfma_f32_16x16x32_bf16(bfr[j], af[i], acc[i][j], 0, 0, 0);
    buf ^= 1;
  }

  // R10 epilogue: reg r spans 4 consecutive C columns; aligned u16x4 stores.
  // (byte addr = (grow*N + cbase)*2; N%8==0, cbase%4==0 -> 8B aligned)
  #pragma unroll
  for (int i = 0; i < 4; ++i) {
    int grow = bm + wm * 64 + i * 16 + row16;
    if (grow < M) {
      #pragma unroll
      for (int j = 0; j < 4; ++j) {
        int cbase = bn + wn * 64 + j * 16 + q * 4;
        if (cbase < N) {
          u16x4 o;
          #pragma unroll
          for (int r = 0; r < 4; ++r) {
            float val = acc[i][j][r];
            if (BIAS_RELU) { val += bias[cbase + r]; val = fmaxf(val, 0.f); }
            o[r] = f2bf(val);
          }
          *(u16x4*)(C + (size_t)grow * N + cbase) = o;
        }
      }
    }
  }
}

static inline int gemm_grid(int M, int N) {
  int gm = (M + BM - 1) / BM;
  int gn = (N + BN - 1) / BN;
  int rows_per_xcd = (gm + 7) / 8;
  return rows_per_xcd * gn * 8;
}

// ---------------- launch ----------------

extern "C" void kernel_launch(void* const* d_in, const int* in_sizes, int n_in,
                              void* d_out, int out_size, void* d_ws, size_t ws_size,
                              hipStream_t stream) {
  const float* x   = (const float*)d_in[0];
  const int* ei    = (const int*)d_in[1];
  const int* src   = ei;
  const int* dst   = ei + NE;
  const float* W1  = (const float*)d_in[2];
  const float* b1  = (const float*)d_in[3];
  const float* W2  = (const float*)d_in[4];
  const float* b2  = (const float*)d_in[5];
  const float* W3  = (const float*)d_in[6];
  const float* b3  = (const float*)d_in[7];
  const float* W4  = (const float*)d_in[8];
  const float* b4  = (const float*)d_in[9];
  const float* W5  = (const float*)d_in[10];
  const float* b5  = (const float*)d_in[11];
  float* out_h = (float*)d_out;                       // 50000 x 192
  float* out_o = (float*)d_out + (size_t)NN * 192;    // 50000 x 5

  char* p = (char*)d_ws;
  auto alloc = [&](size_t bytes) { char* r = p; p += (bytes + 255) & ~(size_t)255; return r; };
  int*   deg      = (int*)alloc((size_t)NN * 4);
  int*   cursor   = (int*)alloc((size_t)NN * 4);
  float* dinv     = (float*)alloc((size_t)NN * 4);
  int*   offs     = (int*)alloc((size_t)(NN + 1) * 4);
  int*   bsum     = (int*)alloc((size_t)256 * 4);
  int2*  csr_pack = (int2*)alloc((size_t)NE * 8);
  u16* W1t = (u16*)alloc((size_t)768 * 1536 * 2);
  u16* W2t = (u16*)alloc((size_t)1536 * 768 * 2);
  u16* W3t = (u16*)alloc((size_t)768 * 384 * 2);
  u16* W4t = (u16*)alloc((size_t)384 * 192 * 2);
  u16* W5t = (u16*)alloc((size_t)192 * 5 * 2);
  u16* B0 = (u16*)alloc((size_t)NN * 768 * 2);
  u16* B1 = (u16*)alloc((size_t)NN * 768 * 2);
  u16* B2 = (u16*)alloc((size_t)NN * 1536 * 2);

  u16* xb  = B0;
  u16* a0  = B1;
  u16* h1  = B2;
  u16* g2  = B0;
  u16* h2  = B1;
  u16* g3  = B0;
  u16* h3  = B2;
  u16* g4  = B0;
  u16* h4b = B1;
  u16* g5p = B0;   // padded NN x 8

  const int M = NN;
  const int NBLK = (NN + 255) / 256;   // 196 blocks

  // degree / CSR build (R9: dinv fused into scan_part1)
  zero2_kernel<<<NBLK, 256, 0, stream>>>(deg, cursor, NN);
  count_deg_kernel<<<(NE + 255) / 256, 256, 0, stream>>>(dst, deg, NE);
  scan_part1<<<NBLK, 256, 0, stream>>>(deg, bsum, dinv, NN);
  scan_part2<<<1, 256, 0, stream>>>(bsum, offs + NN, NBLK);
  scan_part3<<<NBLK, 256, 0, stream>>>(deg, bsum, offs, NN);
  csr_fill_kernel<<<(NE + 255) / 256, 256, 0, stream>>>(src, dst, offs, cursor, dinv,
                                                        csr_pack, NE);
  // dtype conversions (R5: vectorized f2bf; all weight transposes in one launch)
  f2bf4_kernel<<<((NN * 768 / 4) + 255) / 256, 256, 0, stream>>>(x, xb, NN * 768 / 4);
  wt_all_kernel<<<(WT_O5 + 255) / 256, 256, 0, stream>>>(W1, W1t, W2, W2t, W3, W3t,
                                                         W4, W4t, W5, W5t);

  dim3 blk(256);

  // layer 1: aggregate-first  (Ahat x) W1 + b1, relu
  agg16_kernel<48, false, false><<<(NN * 48 + 255) / 256, blk, 0, stream>>>(
      xb, offs, csr_pack, dinv, nullptr, a0);
  gemm_bt_kernel<true><<<gemm_grid(M, 1536), blk, 0, stream>>>(
      a0, W1t, h1, b1, M, 1536, 768);

  // layer 2
  gemm_bt_kernel<false><<<gemm_grid(M, 768), blk, 0, stream>>>(
      h1, W2t, g2, nullptr, M, 768, 1536);
  agg16_kernel<48, true, true><<<(NN * 48 + 255) / 256, blk, 0, stream>>>(
      g2, offs, csr_pack, dinv, b2, h2);

  // layer 3
  gemm_bt_kernel<false><<<gemm_grid(M, 384), blk, 0, stream>>>(
      h2, W3t, g3, nullptr, M, 384, 768);
  agg8_kernel<48, true, true, true, false><<<(NN * 48 + 255) / 256, blk, 0, stream>>>(
      g3, offs, csr_pack, dinv, b3, h3, nullptr);

  // layer 4 (output 0: fp32 h to d_out, bf16 copy for layer 5)
  gemm_bt_kernel<false><<<gemm_grid(M, 192), blk, 0, stream>>>(
      h3, W4t, g4, nullptr, M, 192, 384);
  agg8_kernel<24, true, true, true, true><<<(NN * 24 + 255) / 256, blk, 0, stream>>>(
      g4, offs, csr_pack, dinv, b4, h4b, out_h);

  // layer 5 (output 1): skinny row-dot GEMM (padded rows) + u16x8 aggregation
  gemm5_kernel<<<NBLK, 256, 0, stream>>>(h4b, W5t, g5p);
  agg_small5_kernel<<<NBLK, 256, 0, stream>>>(g5p, offs, csr_pack, dinv, b5, out_o);
}

// Round 11
// 1016.883 us; speedup vs baseline: 1.0009x; 1.0003x over previous
//
#include <hip/hip_runtime.h>
#include <stdint.h>

typedef unsigned short u16;
typedef unsigned int   u32;

#define NN 50000
#define NE 400000

typedef __bf16 bf16x8 __attribute__((ext_vector_type(8)));
typedef u16    u16x8  __attribute__((ext_vector_type(8)));
typedef u16    u16x4  __attribute__((ext_vector_type(4)));
typedef float  f32x4  __attribute__((ext_vector_type(4)));

__device__ __forceinline__ float bf2f(u16 b) {
  union { u32 u; float f; } v; v.u = ((u32)b) << 16; return v.f;
}
__device__ __forceinline__ u16 f2bf(float f) {
  union { float f; u32 u; } v; v.f = f;
  u32 r = v.u + 0x7fffu + ((v.u >> 16) & 1u);
  return (u16)(r >> 16);
}

// ---------------- setup kernels ----------------
// R11: byte-identical resubmit of R10 (variance/pinning probe — see round notes).

// R5: fused zero of deg + cursor (one launch instead of two)
__global__ void zero2_kernel(int* __restrict__ a, int* __restrict__ b, int n) {
  int i = blockIdx.x * blockDim.x + threadIdx.x;
  if (i < n) { a[i] = 0; b[i] = 0; }
}

__global__ void count_deg_kernel(const int* __restrict__ dst, int* __restrict__ deg, int e) {
  int i = blockIdx.x * blockDim.x + threadIdx.x;
  if (i < e) atomicAdd(&deg[dst[i]], 1);
}

// R7: multi-block 3-launch scan (verified R8: replaced 25-40us serial scan).
// R9: dinv computation fused into part1 (it already reads deg[i]).
__global__ void scan_part1(const int* __restrict__ counts, int* __restrict__ bsum,
                           float* __restrict__ dinv, int n) {
  __shared__ int ws[4];
  int tid = threadIdx.x;
  int i = blockIdx.x * 256 + tid;
  int v = (i < n) ? counts[i] : 0;
  if (i < n) dinv[i] = rsqrtf((float)v + 1.0f);
  int s = v;
  #pragma unroll
  for (int off = 1; off < 64; off <<= 1) s += __shfl_xor(s, off, 64);
  int lane = tid & 63, wid = tid >> 6;
  if (lane == 0) ws[wid] = s;
  __syncthreads();
  if (tid == 0) bsum[blockIdx.x] = ws[0] + ws[1] + ws[2] + ws[3];
}
// part2: single block, exclusive-scan bsum in place (nb <= 256); total -> *totp
__global__ void scan_part2(int* __restrict__ bsum, int* __restrict__ totp, int nb) {
  __shared__ int ws[5];
  int tid = threadIdx.x;
  int v = (tid < nb) ? bsum[tid] : 0;
  int lane = tid & 63, wid = tid >> 6;
  int s = v;
  #pragma unroll
  for (int off = 1; off < 64; off <<= 1) {
    int t = __shfl_up(s, off, 64);
    if (lane >= off) s += t;
  }
  if (lane == 63) ws[wid] = s;
  __syncthreads();
  if (tid == 0) {
    int a = 0;
    #pragma unroll
    for (int w = 0; w < 4; ++w) { int t = ws[w]; ws[w] = a; a += t; }
    ws[4] = a;
  }
  __syncthreads();
  int ex = ws[wid] + s - v;
  if (tid < nb) bsum[tid] = ex;
  if (tid == 0) *totp = ws[4];
}
// part3: block-local exclusive scan + bsum[block] -> offsets[i]
__global__ void scan_part3(const int* __restrict__ counts, const int* __restrict__ bsum,
                           int* __restrict__ offsets, int n) {
  __shared__ int ws[5];
  int tid = threadIdx.x;
  int i = blockIdx.x * 256 + tid;
  int v = (i < n) ? counts[i] : 0;
  int lane = tid & 63, wid = tid >> 6;
  int s = v;
  #pragma unroll
  for (int off = 1; off < 64; off <<= 1) {
    int t = __shfl_up(s, off, 64);
    if (lane >= off) s += t;
  }
  if (lane == 63) ws[wid] = s;
  __syncthreads();
  if (tid == 0) {
    int a = 0;
    #pragma unroll
    for (int w = 0; w < 4; ++w) { int t = ws[w]; ws[w] = a; a += t; }
  }
  __syncthreads();
  int ex = ws[wid] + s - v;
  if (i < n) offsets[i] = bsum[blockIdx.x] + ex;
}

__global__ void csr_fill_kernel(const int* __restrict__ src, const int* __restrict__ dst,
                                const int* __restrict__ offsets, int* __restrict__ cursor,
                                const float* __restrict__ dinv,
                                int2* __restrict__ csr_pack, int e) {
  int i = blockIdx.x * blockDim.x + threadIdx.x;
  if (i < e) {
    int s = src[i], d = dst[i];
    int pos = offsets[d] + atomicAdd(&cursor[d], 1);
    float nr = dinv[s] * dinv[d];
    csr_pack[pos] = make_int2(s, __float_as_int(nr));
  }
}

// R5: vectorized f2bf (float4 in, 4x bf16 out) — G13, n must be /4
__global__ void f2bf4_kernel(const float* __restrict__ in, u16* __restrict__ out, int n4) {
  int i = blockIdx.x * blockDim.x + threadIdx.x;
  if (i < n4) {
    f32x4 v = *(const f32x4*)(in + (size_t)i * 4);
    u16x4 o;
    #pragma unroll
    for (int k = 0; k < 4; ++k) o[k] = f2bf(v[k]);
    *(u16x4*)(out + (size_t)i * 4) = o;
  }
}

// W (K x N, row-major fp32) -> Wt (N x K, row-major bf16)
__device__ __forceinline__ void wt_one(const float* W, u16* Wt, int i, int K, int N) {
  int k = i / N;
  int n2 = i - k * N;
  Wt[n2 * K + k] = f2bf(W[i]);
}

// R5: all 5 weight transposes in one launch (ranges hardcoded)
#define WT_O1 1179648   // 768*1536
#define WT_O2 2359296   // +1536*768
#define WT_O3 2654208   // +768*384
#define WT_O4 2727936   // +384*192
#define WT_O5 2728896   // +192*5
__global__ void wt_all_kernel(const float* __restrict__ W1, u16* __restrict__ W1t,
                              const float* __restrict__ W2, u16* __restrict__ W2t,
                              const float* __restrict__ W3, u16* __restrict__ W3t,
                              const float* __restrict__ W4, u16* __restrict__ W4t,
                              const float* __restrict__ W5, u16* __restrict__ W5t) {
  int i = blockIdx.x * blockDim.x + threadIdx.x;
  if (i < WT_O1)      wt_one(W1, W1t, i, 768, 1536);
  else if (i < WT_O2) wt_one(W2, W2t, i - WT_O1, 1536, 768);
  else if (i < WT_O3) wt_one(W3, W3t, i - WT_O2, 768, 384);
  else if (i < WT_O4) wt_one(W4, W4t, i - WT_O3, 384, 192);
  else if (i < WT_O5) wt_one(W5, W5t, i - WT_O4, 192, 5);
}

// ---------------- aggregation ----------------
// R8 verdict: agg16's x2 MLP was neutral -> the F=768 aggregations are
// gather-BANDWIDTH-bound (~4.2 TB/s effective on 614 MB/layer = ~145us floor).
// Byte reduction (fp8) would blow the absmax budget. Kernels kept as-is.

template<int G2, bool HAS_BIAS, bool RELU>
__global__ __launch_bounds__(256) void agg16_kernel(
    const u16* __restrict__ g, const int* __restrict__ rowptr,
    const int2* __restrict__ csr_pack,
    const float* __restrict__ dinv, const float* __restrict__ bias,
    u16* __restrict__ outb)
{
  constexpr int F = G2 * 16;
  int idx = blockIdx.x * blockDim.x + threadIdx.x;
  if (idx >= NN * G2) return;
  int v = idx / G2;
  int t = idx - v * G2;
  const u16* base0 = g + t * 8;
  const u16* base1 = g + (t + G2) * 8;

  float acc0[8], acc1[8];
  #pragma unroll
  for (int k = 0; k < 8; ++k) { acc0[k] = 0.f; acc1[k] = 0.f; }

  int e0 = rowptr[v], e1 = rowptr[v + 1];
  int e = e0;
  for (; e + 3 < e1; e += 4) {
    int2 p0 = csr_pack[e];
    int2 p1 = csr_pack[e + 1];
    int2 p2 = csr_pack[e + 2];
    int2 p3 = csr_pack[e + 3];
    u16x8 a0 = *(const u16x8*)(base0 + (size_t)p0.x * F);
    u16x8 b0 = *(const u16x8*)(base1 + (size_t)p0.x * F);
    u16x8 a1 = *(const u16x8*)(base0 + (size_t)p1.x * F);
    u16x8 b1 = *(const u16x8*)(base1 + (size_t)p1.x * F);
    u16x8 a2 = *(const u16x8*)(base0 + (size_t)p2.x * F);
    u16x8 b2 = *(const u16x8*)(base1 + (size_t)p2.x * F);
    u16x8 a3 = *(const u16x8*)(base0 + (size_t)p3.x * F);
    u16x8 b3 = *(const u16x8*)(base1 + (size_t)p3.x * F);
    float n0 = __int_as_float(p0.y), n1 = __int_as_float(p1.y);
    float n2 = __int_as_float(p2.y), n3 = __int_as_float(p3.y);
    #pragma unroll
    for (int k = 0; k < 8; ++k) { acc0[k] += n0 * bf2f(a0[k]); acc1[k] += n0 * bf2f(b0[k]); }
    #pragma unroll
    for (int k = 0; k < 8; ++k) { acc0[k] += n1 * bf2f(a1[k]); acc1[k] += n1 * bf2f(b1[k]); }
    #pragma unroll
    for (int k = 0; k < 8; ++k) { acc0[k] += n2 * bf2f(a2[k]); acc1[k] += n2 * bf2f(b2[k]); }
    #pragma unroll
    for (int k = 0; k < 8; ++k) { acc0[k] += n3 * bf2f(a3[k]); acc1[k] += n3 * bf2f(b3[k]); }
  }
  for (; e < e1; ++e) {
    int2 p0 = csr_pack[e];
    u16x8 a0 = *(const u16x8*)(base0 + (size_t)p0.x * F);
    u16x8 b0 = *(const u16x8*)(base1 + (size_t)p0.x * F);
    float n0 = __int_as_float(p0.y);
    #pragma unroll
    for (int k = 0; k < 8; ++k) { acc0[k] += n0 * bf2f(a0[k]); acc1[k] += n0 * bf2f(b0[k]); }
  }

  float sv = dinv[v]; sv *= sv;
  u16x8 s0 = *(const u16x8*)(base0 + (size_t)v * F);
  u16x8 s1 = *(const u16x8*)(base1 + (size_t)v * F);
  u16x8 o0, o1;
  #pragma unroll
  for (int k = 0; k < 8; ++k) {
    float v0 = acc0[k] + sv * bf2f(s0[k]);
    float v1 = acc1[k] + sv * bf2f(s1[k]);
    if (HAS_BIAS) { v0 += bias[t * 8 + k]; v1 += bias[(t + G2) * 8 + k]; }
    if (RELU) { v0 = fmaxf(v0, 0.f); v1 = fmaxf(v1, 0.f); }
    o0[k] = f2bf(v0); o1[k] = f2bf(v1);
  }
  *(u16x8*)(outb + (size_t)v * F + t * 8) = o0;
  *(u16x8*)(outb + (size_t)v * F + (t + G2) * 8) = o1;
}

// R4-verified agg8 kept for F=384/192 (halving threads/node there worsens
// wave-max-degree; R5 lesson).
template<int G, bool HAS_BIAS, bool RELU, bool OUT_BF, bool OUT_F32>
__global__ __launch_bounds__(256) void agg8_kernel(
    const u16* __restrict__ g, const int* __restrict__ rowptr,
    const int2* __restrict__ csr_pack,
    const float* __restrict__ dinv, const float* __restrict__ bias,
    u16* __restrict__ outb, float* __restrict__ outf)
{
  constexpr int F = G * 8;
  int idx = blockIdx.x * blockDim.x + threadIdx.x;
  if (idx >= NN * G) return;
  int v = idx / G;
  int g8 = idx - v * G;
  const u16* base = g + g8 * 8;

  float acc[8];
  #pragma unroll
  for (int k = 0; k < 8; ++k) acc[k] = 0.f;

  int e0 = rowptr[v], e1 = rowptr[v + 1];
  int e = e0;
  for (; e + 3 < e1; e += 4) {
    int2 p0 = csr_pack[e];
    int2 p1 = csr_pack[e + 1];
    int2 p2 = csr_pack[e + 2];
    int2 p3 = csr_pack[e + 3];
    u16x8 r0 = *(const u16x8*)(base + (size_t)p0.x * F);
    u16x8 r1 = *(const u16x8*)(base + (size_t)p1.x * F);
    u16x8 r2 = *(const u16x8*)(base + (size_t)p2.x * F);
    u16x8 r3 = *(const u16x8*)(base + (size_t)p3.x * F);
    float n0 = __int_as_float(p0.y), n1 = __int_as_float(p1.y);
    float n2 = __int_as_float(p2.y), n3 = __int_as_float(p3.y);
    #pragma unroll
    for (int k = 0; k < 8; ++k) acc[k] += n0 * bf2f(r0[k]);
    #pragma unroll
    for (int k = 0; k < 8; ++k) acc[k] += n1 * bf2f(r1[k]);
    #pragma unroll
    for (int k = 0; k < 8; ++k) acc[k] += n2 * bf2f(r2[k]);
    #pragma unroll
    for (int k = 0; k < 8; ++k) acc[k] += n3 * bf2f(r3[k]);
  }
  for (; e < e1; ++e) {
    int2 p0 = csr_pack[e];
    u16x8 r0 = *(const u16x8*)(base + (size_t)p0.x * F);
    float n0 = __int_as_float(p0.y);
    #pragma unroll
    for (int k = 0; k < 8; ++k) acc[k] += n0 * bf2f(r0[k]);
  }

  float sv = dinv[v]; sv *= sv;
  u16x8 sr = *(const u16x8*)(base + (size_t)v * F);
  float vals[8];
  #pragma unroll
  for (int k = 0; k < 8; ++k) {
    float val = acc[k] + sv * bf2f(sr[k]);
    if (HAS_BIAS) val += bias[g8 * 8 + k];
    if (RELU) val = fmaxf(val, 0.f);
    vals[k] = val;
  }
  if (OUT_BF) {
    u16x8 ob;
    #pragma unroll
    for (int k = 0; k < 8; ++k) ob[k] = f2bf(vals[k]);
    *(u16x8*)(outb + (size_t)v * F + g8 * 8) = ob;
  }
  if (OUT_F32) {
    f32x4 o0, o1;
    #pragma unroll
    for (int k = 0; k < 4; ++k) { o0[k] = vals[k]; o1[k] = vals[4 + k]; }
    float* op = outf + (size_t)v * F + g8 * 8;
    *(f32x4*)op = o0;
    *(f32x4*)(op + 4) = o1;
  }
}

// ---------------- layer 5 (N=5): skinny GEMM + aggregation (R9) ----------------

__global__ void gemm5_kernel(const u16* __restrict__ A,      // NN x 192 bf16
                             const u16* __restrict__ W5t,    // 5 x 192 bf16
                             u16* __restrict__ Gp) {         // NN x 8 bf16 (padded)
  int row = blockIdx.x * blockDim.x + threadIdx.x;
  if (row >= NN) return;
  const u16* a = A + (size_t)row * 192;
  float acc[5] = {0.f, 0.f, 0.f, 0.f, 0.f};
  #pragma unroll
  for (int c = 0; c < 24; ++c) {
    u16x8 av = *(const u16x8*)(a + c * 8);
    float af[8];
    #pragma unroll
    for (int k = 0; k < 8; ++k) af[k] = bf2f(av[k]);
    #pragma unroll
    for (int j = 0; j < 5; ++j) {
      u16x8 wv = *(const u16x8*)(W5t + j * 192 + c * 8);
      #pragma unroll
      for (int k = 0; k < 8; ++k) acc[j] += af[k] * bf2f(wv[k]);
    }
  }
  u16x8 o;
  #pragma unroll
  for (int j = 0; j < 5; ++j) o[j] = f2bf(acc[j]);
  o[5] = 0; o[6] = 0; o[7] = 0;
  *(u16x8*)(Gp + (size_t)row * 8) = o;
}

__global__ void agg_small5_kernel(const u16* __restrict__ Gp,   // NN x 8 padded
                                  const int* __restrict__ rowptr,
                                  const int2* __restrict__ csr_pack,
                                  const float* __restrict__ dinv,
                                  const float* __restrict__ bias,
                                  float* __restrict__ out) {    // NN x 5 f32
  int v = blockIdx.x * blockDim.x + threadIdx.x;
  if (v >= NN) return;
  float acc[5] = {0.f, 0.f, 0.f, 0.f, 0.f};
  int e1 = rowptr[v + 1];
  for (int e = rowptr[v]; e < e1; ++e) {
    int2 p = csr_pack[e];
    u16x8 r = *(const u16x8*)(Gp + (size_t)p.x * 8);
    float n = __int_as_float(p.y);
    #pragma unroll
    for (int j = 0; j < 5; ++j) acc[j] += n * bf2f(r[j]);
  }
  float dv = dinv[v]; dv *= dv;
  u16x8 s = *(const u16x8*)(Gp + (size_t)v * 8);
  #pragma unroll
  for (int j = 0; j < 5; ++j)
    out[(size_t)v * 5 + j] = acc[j] + dv * bf2f(s[j]) + bias[j];
}

// ---------------- GEMM (A: MxK bf16 row-major, Bt: NxK bf16 row-major) ----------------
// R5 DECISION: 128x128 m97-structure for ALL big layers (the 256x256 deep-pipeline
// arc R1/R3/R4 never beat it). XCD supertile + quad swizzle (conflicts 0) + dbuf
// K-loop + __launch_bounds__(256,4).
// R10 (verified): swapped-operand MFMA epilogue — mfma(bfr, af, acc) computes the
// transposed tile; D-mapping lands reg r on 4 consecutive C columns -> 16 aligned
// 8B u16x4 stores/thread. Measured: 199.7->188.1us, WRITE 178->160.6MB,
// MfmaUtil 25.4->27.3%, conflicts 0.

#define BM 128
#define BN 128
#define BK 32

// gfx9 s_waitcnt simm16: vmcnt[3:0]|expcnt[6:4]|lgkmcnt[11:8]|vmcnt_hi[15:14]
#define WAIT_VMCNT4 0x0F74   // vmcnt(4), lgkm/exp = no-wait
#define WAIT_VMCNT0 0x0F70   // vmcnt(0), lgkm/exp = no-wait

__device__ __forceinline__ void gl_lds16(const void* g, void* l) {
  __builtin_amdgcn_global_load_lds((const __attribute__((address_space(1))) void*)g,
                                   (__attribute__((address_space(3))) void*)l, 16, 0, 0);
}

template<bool BIAS_RELU>
__global__ __launch_bounds__(256, 4) void gemm_bt_kernel(
    const u16* __restrict__ A, const u16* __restrict__ Bt,
    u16* __restrict__ C, const float* __restrict__ bias,
    int M, int N, int K)
{
  __shared__ __align__(16) u16 As[2][BM * BK];
  __shared__ __align__(16) u16 Bs[2][BN * BK];
  int gm = (M + BM - 1) / BM;
  int gn = (N + BN - 1) / BN;
  int bid = blockIdx.x;
  int xcd = bid & 7;
  int t = bid >> 3;
  int trow = t / gn;
  int bn_i = t - trow * gn;
  int row = trow * 8 + xcd;
  if (row >= gm) return;
  int bm = row * BM, bn = bn_i * BN;

  int tid = threadIdx.x;
  int wave = tid >> 6, lane = tid & 63;
  int wm = wave & 1, wn = wave >> 1;

  // staging: 4 lanes per 32-elem row; logical quad permuted -> swizzled LDS layout
  int srow = tid >> 2;                                // 0..63
  int sq_log = ((tid & 3) - ((tid >> 3) & 3)) & 3;    // logical quad this lane stages
  int ar0 = min(bm + srow, M - 1);
  int ar1 = min(bm + 64 + srow, M - 1);
  int br0 = min(bn + srow, N - 1);
  int br1 = min(bn + 64 + srow, N - 1);
  const u16* ag0 = A + (size_t)ar0 * K + sq_log * 8;
  const u16* ag1 = A + (size_t)ar1 * K + sq_log * 8;
  const u16* bg0 = Bt + (size_t)br0 * K + sq_log * 8;
  const u16* bg1 = Bt + (size_t)br1 * K + sq_log * 8;
  int la0 = (wave * 16) * BK;
  int la1 = (64 + wave * 16) * BK;

  f32x4 acc[4][4];
  #pragma unroll
  for (int i = 0; i < 4; ++i)
    #pragma unroll
    for (int j = 0; j < 4; ++j)
      acc[i][j] = (f32x4){0.f, 0.f, 0.f, 0.f};

  int row16 = lane & 15, q = lane >> 4;
  int perm = (q + (row16 >> 1)) & 3;                  // physical quad for logical quad q
  int ard = (wm * 64 + row16) * BK + perm * 8;
  int brd = (wn * 64 + row16) * BK + perm * 8;

  const int iters = K / BK;

  // prologue: stage tile 0 into buffer 0
  gl_lds16(ag0, &As[0][la0]);
  gl_lds16(ag1, &As[0][la1]);
  gl_lds16(bg0, &Bs[0][la0]);
  gl_lds16(bg1, &Bs[0][la1]);

  int buf = 0;
  for (int it = 0; it < iters; ++it) {
    __builtin_amdgcn_s_barrier();
    if (it + 1 < iters) {
      int kn = (it + 1) * BK;
      gl_lds16(ag0 + kn, &As[buf ^ 1][la0]);
      gl_lds16(ag1 + kn, &As[buf ^ 1][la1]);
      gl_lds16(bg0 + kn, &Bs[buf ^ 1][la0]);
      gl_lds16(bg1 + kn, &Bs[buf ^ 1][la1]);
      __builtin_amdgcn_s_waitcnt(WAIT_VMCNT4);  // wait only current buf's 4 loads
    } else {
      __builtin_amdgcn_s_waitcnt(WAIT_VMCNT0);
    }
    __builtin_amdgcn_s_barrier();

    bf16x8 af[4], bfr[4];
    #pragma unroll
    for (int i = 0; i < 4; ++i) af[i] = *(const bf16x8*)(&As[buf][ard + i * 16 * BK]);
    #pragma unroll
    for (int j = 0; j < 4; ++j) bfr[j] = *(const bf16x8*)(&Bs[buf][brd + j * 16 * BK]);
    // R10: operands swapped -> acc[i][j] holds the transposed sub-tile
    #pragma unroll
    for (int i = 0; i < 4; ++i)
      #pragma unroll
      for (int j = 0; j < 4; ++j)
        acc[i][j] = __builtin_amdgcn_mfma_f32_16x16x32_bf16(bfr[j], af[i], acc[i][j], 0, 0, 0);
    buf ^= 1;
  }

  // R10 epilogue: reg r spans 4 consecutive C columns; aligned u16x4 stores.
  // (byte addr = (grow*N + cbase)*2; N%8==0, cbase%4==0 -> 8B aligned)
  #pragma unroll
  for (int i = 0; i < 4; ++i) {
    int grow = bm + wm * 64 + i * 16 + row16;
    if (grow < M) {
      #pragma unroll
      for (int j = 0; j < 4; ++j) {
        int cbase = bn + wn * 64 + j * 16 + q * 4;
        if (cbase < N) {
          u16x4 o;
          #pragma unroll
          for (int r = 0; r < 4; ++r) {
            float val = acc[i][j][r];
            if (BIAS_RELU) { val += bias[cbase + r]; val = fmaxf(val, 0.f); }
            o[r] = f2bf(val);
          }
          *(u16x4*)(C + (size_t)grow * N + cbase) = o;
        }
      }
    }
  }
}

static inline int gemm_grid(int M, int N) {
  int gm = (M + BM - 1) / BM;
  int gn = (N + BN - 1) / BN;
  int rows_per_xcd = (gm + 7) / 8;
  return rows_per_xcd * gn * 8;
}

// ---------------- launch ----------------

extern "C" void kernel_launch(void* const* d_in, const int* in_sizes, int n_in,
                              void* d_out, int out_size, void* d_ws, size_t ws_size,
                              hipStream_t stream) {
  const float* x   = (const float*)d_in[0];
  const int* ei    = (const int*)d_in[1];
  const int* src   = ei;
  const int* dst   = ei + NE;
  const float* W1  = (const float*)d_in[2];
  const float* b1  = (const float*)d_in[3];
  const float* W2  = (const float*)d_in[4];
  const float* b2  = (const float*)d_in[5];
  const float* W3  = (const float*)d_in[6];
  const float* b3  = (const float*)d_in[7];
  const float* W4  = (const float*)d_in[8];
  const float* b4  = (const float*)d_in[9];
  const float* W5  = (const float*)d_in[10];
  const float* b5  = (const float*)d_in[11];
  float* out_h = (float*)d_out;                       // 50000 x 192
  float* out_o = (float*)d_out + (size_t)NN * 192;    // 50000 x 5

  char* p = (char*)d_ws;
  auto alloc = [&](size_t bytes) { char* r = p; p += (bytes + 255) & ~(size_t)255; return r; };
  int*   deg      = (int*)alloc((size_t)NN * 4);
  int*   cursor   = (int*)alloc((size_t)NN * 4);
  float* dinv     = (float*)alloc((size_t)NN * 4);
  int*   offs     = (int*)alloc((size_t)(NN + 1) * 4);
  int*   bsum     = (int*)alloc((size_t)256 * 4);
  int2*  csr_pack = (int2*)alloc((size_t)NE * 8);
  u16* W1t = (u16*)alloc((size_t)768 * 1536 * 2);
  u16* W2t = (u16*)alloc((size_t)1536 * 768 * 2);
  u16* W3t = (u16*)alloc((size_t)768 * 384 * 2);
  u16* W4t = (u16*)alloc((size_t)384 * 192 * 2);
  u16* W5t = (u16*)alloc((size_t)192 * 5 * 2);
  u16* B0 = (u16*)alloc((size_t)NN * 768 * 2);
  u16* B1 = (u16*)alloc((size_t)NN * 768 * 2);
  u16* B2 = (u16*)alloc((size_t)NN * 1536 * 2);

  u16* xb  = B0;
  u16* a0  = B1;
  u16* h1  = B2;
  u16* g2  = B0;
  u16* h2  = B1;
  u16* g3  = B0;
  u16* h3  = B2;
  u16* g4  = B0;
  u16* h4b = B1;
  u16* g5p = B0;   // padded NN x 8

  const int M = NN;
  const int NBLK = (NN + 255) / 256;   // 196 blocks

  // degree / CSR build (R9: dinv fused into scan_part1)
  zero2_kernel<<<NBLK, 256, 0, stream>>>(deg, cursor, NN);
  count_deg_kernel<<<(NE + 255) / 256, 256, 0, stream>>>(dst, deg, NE);
  scan_part1<<<NBLK, 256, 0, stream>>>(deg, bsum, dinv, NN);
  scan_part2<<<1, 256, 0, stream>>>(bsum, offs + NN, NBLK);
  scan_part3<<<NBLK, 256, 0, stream>>>(deg, bsum, offs, NN);
  csr_fill_kernel<<<(NE + 255) / 256, 256, 0, stream>>>(src, dst, offs, cursor, dinv,
                                                        csr_pack, NE);
  // dtype conversions (R5: vectorized f2bf; all weight transposes in one launch)
  f2bf4_kernel<<<((NN * 768 / 4) + 255) / 256, 256, 0, stream>>>(x, xb, NN * 768 / 4);
  wt_all_kernel<<<(WT_O5 + 255) / 256, 256, 0, stream>>>(W1, W1t, W2, W2t, W3, W3t,
                                                         W4, W4t, W5, W5t);

  dim3 blk(256);

  // layer 1: aggregate-first  (Ahat x) W1 + b1, relu
  agg16_kernel<48, false, false><<<(NN * 48 + 255) / 256, blk, 0, stream>>>(
      xb, offs, csr_pack, dinv, nullptr, a0);
  gemm_bt_kernel<true><<<gemm_grid(M, 1536), blk, 0, stream>>>(
      a0, W1t, h1, b1, M, 1536, 768);

  // layer 2
  gemm_bt_kernel<false><<<gemm_grid(M, 768), blk, 0, stream>>>(
      h1, W2t, g2, nullptr, M, 768, 1536);
  agg16_kernel<48, true, true><<<(NN * 48 + 255) / 256, blk, 0, stream>>>(
      g2, offs, csr_pack, dinv, b2, h2);

  // layer 3
  gemm_bt_kernel<false><<<gemm_grid(M, 384), blk, 0, stream>>>(
      h2, W3t, g3, nullptr, M, 384, 768);
  agg8_kernel<48, true, true, true, false><<<(NN * 48 + 255) / 256, blk, 0, stream>>>(
      g3, offs, csr_pack, dinv, b3, h3, nullptr);

  // layer 4 (output 0: fp32 h to d_out, bf16 copy for layer 5)
  gemm_bt_kernel<false><<<gemm_grid(M, 192), blk, 0, stream>>>(
      h3, W4t, g4, nullptr, M, 192, 384);
  agg8_kernel<24, true, true, true, true><<<(NN * 24 + 255) / 256, blk, 0, stream>>>(
      g4, offs, csr_pack, dinv, b4, h4b, out_h);

  // layer 5 (output 1): skinny row-dot GEMM (padded rows) + u16x8 aggregation
  gemm5_kernel<<<NBLK, 256, 0, stream>>>(h4b, W5t, g5p);
  agg_small5_kernel<<<NBLK, 256, 0, stream>>>(g5p, offs, csr_pack, dinv, b5, out_o);
}